// Round 4
// baseline (444.435 us; speedup 1.0000x reference)
//
#include <hip/hip_runtime.h>

typedef unsigned long long u64;
typedef unsigned short ushort_t;
typedef float f32x4 __attribute__((ext_vector_type(4)));
typedef short bf16x8 __attribute__((ext_vector_type(8)));
typedef unsigned short ushort8 __attribute__((ext_vector_type(8)));

#define D_DIM   256
#define N_ROWS  16384
#define K_CODES 8192
#define OFF_DIFF 4194304
#define OFF_IND  4194305

// ---------------- ws layout (bytes) for the MFMA path ----------------
#define XH_OFF    0ULL
#define XL_OFF    8388608ULL
#define EHT_OFF   16777216ULL
#define ELT_OFF   20971520ULL
#define ETF_OFF   25165824ULL
#define ENORM_OFF 33554432ULL
#define KEYS_OFF  33587200ULL
#define PV1_OFF   33718272ULL
#define PIDX_OFF  37912576ULL
#define PV2_OFF   42106880ULL
#define WLC_OFF   46301184ULL
#define WL_OFF    46301440ULL
#define PART_OFF  46366976ULL
#define WS_NEED   46375168ULL

#define MARGIN_TH 0.08f

#define GLD(gp, lp) __builtin_amdgcn_global_load_lds( \
    (const __attribute__((address_space(1))) unsigned int*)(const void*)(gp), \
    (__attribute__((address_space(3))) unsigned int*)(void*)(lp), 16, 0, 0)

__device__ __forceinline__ unsigned int fsort(float f) {
    unsigned int u = __float_as_uint(f);
    return (u & 0x80000000u) ? ~u : (u | 0x80000000u);
}
__device__ __forceinline__ ushort_t f2bf(float f) {
    unsigned int u = __float_as_uint(f);
    unsigned int r = (u + 0x7fffu + ((u >> 16) & 1u)) >> 16;
    return (ushort_t)r;
}
__device__ __forceinline__ float bf2f(ushort_t h) {
    return __uint_as_float(((unsigned int)h) << 16);
}

// ================= kernel: split x into bf16 hi/lo =================
__global__ __launch_bounds__(256) void k_split_x(const float* __restrict__ x,
                                                 ushort_t* __restrict__ xh,
                                                 ushort_t* __restrict__ xl) {
    int base = (blockIdx.x * 256 + threadIdx.x) * 8;
    float4 v0 = *reinterpret_cast<const float4*>(&x[base]);
    float4 v1 = *reinterpret_cast<const float4*>(&x[base + 4]);
    float f[8] = {v0.x, v0.y, v0.z, v0.w, v1.x, v1.y, v1.z, v1.w};
    ushort8 h, l;
    #pragma unroll
    for (int i = 0; i < 8; ++i) {
        ushort_t hb = f2bf(f[i]);
        h[i] = (short)hb;
        l[i] = (short)f2bf(f[i] - bf2f(hb));
    }
    *reinterpret_cast<ushort8*>(&xh[base]) = h;
    *reinterpret_cast<ushort8*>(&xl[base]) = l;
}

// ===== kernel: transpose e -> eT (f32) + bf16 hi/lo splits of eT ======
__global__ __launch_bounds__(256) void k_split_eT(const float* __restrict__ e,
                                                  ushort_t* __restrict__ ehT,
                                                  ushort_t* __restrict__ elT,
                                                  float* __restrict__ eTf) {
    __shared__ float tile[64][257];
    const int t = threadIdx.x;
    const int c0 = blockIdx.x * 64;
    for (int it = 0; it < 64; ++it) {
        int d = it * 4 + (t >> 6);
        tile[t & 63][d] = e[d * K_CODES + c0 + (t & 63)];
    }
    __syncthreads();
    for (int cc = 0; cc < 64; ++cc) {
        float v = tile[cc][t];
        ushort_t hb = f2bf(v);
        size_t o = (size_t)(c0 + cc) * 256 + t;
        ehT[o] = hb;
        elT[o] = f2bf(v - bf2f(hb));
        eTf[o] = v;
    }
}

// ================= kernel: ||e_k||^2 (+ worklist count init) ==========
__global__ __launch_bounds__(256) void k_norms(const float* __restrict__ e,
                                               float* __restrict__ enorm,
                                               int* __restrict__ wlc) {
    int k = blockIdx.x * 256 + threadIdx.x;
    float s = 0.f;
    #pragma unroll 8
    for (int d = 0; d < D_DIM; ++d) {
        float v = e[d * K_CODES + k];
        s = fmaf(v, v, s);
    }
    enorm[k] = s;
    if (k == 0) *wlc = 0;
}

// ============ kernel: MFMA distance GEMM + in-lane top-2 ==============
// R4: TRANSPOSED operands: A = codes (ehT/elT), B = x-rows (xh/xl).
// C row-dim <-> codes (in-register per lane), col-dim (lane&15) <-> x-row.
// Each lane holds 16 code-candidates per ni -> top-2 fold is in-lane;
// running (v1,i1,v2) per ni (12 VGPRs) folds across 8 in-block code
// chunks (grid.y=8); heavy cross-lane reduce runs ONCE per block.
__global__ __launch_bounds__(256, 3) void k_mfma(const ushort_t* __restrict__ xh,
                                                 const ushort_t* __restrict__ xl,
                                                 const ushort_t* __restrict__ ehT,
                                                 const ushort_t* __restrict__ elT,
                                                 const float* __restrict__ enorm,
                                                 float* __restrict__ pv1,
                                                 int* __restrict__ pidx,
                                                 float* __restrict__ pv2) {
    __shared__ short Ah[4096], Al[4096], Bh[4096], Bl[4096];
    __shared__ float mg_v1[2][128];
    __shared__ float mg_v2[2][128];
    __shared__ int   mg_i1[2][128];
    __shared__ float en_s[128];
    const int tid = threadIdx.x;
    const int l = tid & 63, w = tid >> 6;
    const int wm = w >> 1, wn = w & 1;   // wm: x-row half, wn: code half
    const int r0 = blockIdx.x * 128;
    const int cbase0 = blockIdx.y * 1024;

    // staging: lane l -> local row rl = l>>2, slot = l&3; LDS[row][slot]
    // holds k-chunk g = slot ^ ((row>>1)&3)  (2-way-optimal swizzle).
    const int rl = l >> 2;
    const int g = (l & 3) ^ ((rl >> 1) & 3);
    const int rowL0 = w * 32 + rl;
    const size_t boff = (size_t)(r0 + rowL0) * 256 + g * 8;  // x side (B)
    short* Adst  = Ah + w * 1024;   // inst1 at +512 (rows +16)
    short* Aldst = Al + w * 1024;
    short* Bdst  = Bh + w * 1024;
    short* Bldst = Bl + w * 1024;

    const int fr = l & 15, kg = l >> 4;

    float v1[4], v2[4];
    int   i1[4];
    #pragma unroll
    for (int ni = 0; ni < 4; ++ni) { v1[ni] = 1e30f; v2[ni] = 1e30f; i1[ni] = 0; }

    for (int ch = 0; ch < 8; ++ch) {
        const int cb = cbase0 + ch * 128;
        __syncthreads();   // protect en_s from previous chunk's epilogue reads
        if (tid < 128) en_s[tid] = enorm[cb + tid];
        const size_t aoff = (size_t)(cb + rowL0) * 256 + g * 8;  // e side (A)

        f32x4 acc[4][4];
        #pragma unroll
        for (int mi = 0; mi < 4; ++mi)
            #pragma unroll
            for (int ni = 0; ni < 4; ++ni)
                #pragma unroll
                for (int q = 0; q < 4; ++q) acc[mi][ni][q] = 0.f;

        for (int kt = 0; kt < 8; ++kt) {
            const int ko = kt * 32;
            GLD(&ehT[aoff + ko], Adst);
            GLD(&ehT[aoff + ko + 4096], Adst + 512);
            GLD(&elT[aoff + ko], Aldst);
            GLD(&elT[aoff + ko + 4096], Aldst + 512);
            GLD(&xh[boff + ko], Bdst);
            GLD(&xh[boff + ko + 4096], Bdst + 512);
            GLD(&xl[boff + ko], Bldst);
            GLD(&xl[boff + ko + 4096], Bldst + 512);
            __syncthreads();

            bf16x8 a_h[4], a_l[4], b_h[4], b_l[4];
            #pragma unroll
            for (int mi = 0; mi < 4; ++mi) {      // A rows = codes
                int rf = wn * 64 + mi * 16 + fr;
                int idx = rf * 32 + ((kg ^ ((rf >> 1) & 3)) * 8);
                a_h[mi] = *reinterpret_cast<const bf16x8*>(&Ah[idx]);
                a_l[mi] = *reinterpret_cast<const bf16x8*>(&Al[idx]);
            }
            #pragma unroll
            for (int ni = 0; ni < 4; ++ni) {      // B cols = x-rows
                int cf = wm * 64 + ni * 16 + fr;
                int idx = cf * 32 + ((kg ^ ((cf >> 1) & 3)) * 8);
                b_h[ni] = *reinterpret_cast<const bf16x8*>(&Bh[idx]);
                b_l[ni] = *reinterpret_cast<const bf16x8*>(&Bl[idx]);
            }
            #pragma unroll
            for (int mi = 0; mi < 4; ++mi)
                #pragma unroll
                for (int ni = 0; ni < 4; ++ni) {
                    acc[mi][ni] = __builtin_amdgcn_mfma_f32_16x16x32_bf16(a_h[mi], b_h[ni], acc[mi][ni], 0, 0, 0);
                    acc[mi][ni] = __builtin_amdgcn_mfma_f32_16x16x32_bf16(a_h[mi], b_l[ni], acc[mi][ni], 0, 0, 0);
                    acc[mi][ni] = __builtin_amdgcn_mfma_f32_16x16x32_bf16(a_l[mi], b_h[ni], acc[mi][ni], 0, 0, 0);
                }
            __syncthreads();
        }

        // fold this chunk's 16 in-lane code candidates per ni into state
        float en_r[4][4];
        #pragma unroll
        for (int mi = 0; mi < 4; ++mi)
            #pragma unroll
            for (int r = 0; r < 4; ++r)
                en_r[mi][r] = en_s[wn * 64 + mi * 16 + kg * 4 + r];
        const int cwn = cb + wn * 64 + kg * 4;
        #pragma unroll
        for (int ni = 0; ni < 4; ++ni)
            #pragma unroll
            for (int mi = 0; mi < 4; ++mi)
                #pragma unroll
                for (int r = 0; r < 4; ++r) {
                    float dv = fmaf(-2.f, acc[mi][ni][r], en_r[mi][r]);
                    int c = cwn + mi * 16 + r;
                    if (dv < v1[ni]) { v2[ni] = v1[ni]; v1[ni] = dv; i1[ni] = c; }
                    else v2[ni] = fminf(v2[ni], dv);
                }
    }

    // final: reduce over the 4 kg lanes (xor 16, 32), then wn-half merge
    #pragma unroll
    for (int ni = 0; ni < 4; ++ni) {
        #pragma unroll
        for (int m = 16; m <= 32; m <<= 1) {
            float ov1 = __shfl_xor(v1[ni], m, 64);
            int   oi1 = __shfl_xor(i1[ni], m, 64);
            float ov2 = __shfl_xor(v2[ni], m, 64);
            bool better = (ov1 < v1[ni]) || (ov1 == v1[ni] && oi1 < i1[ni]);
            float nv2 = fminf(fminf(v2[ni], ov2), better ? v1[ni] : ov1);
            if (better) { v1[ni] = ov1; i1[ni] = oi1; }
            v2[ni] = nv2;
        }
        if (l < 16) {
            int lr = wm * 64 + ni * 16 + l;   // local x-row 0..127
            mg_v1[wn][lr] = v1[ni];
            mg_i1[wn][lr] = i1[ni];
            mg_v2[wn][lr] = v2[ni];
        }
    }

    __syncthreads();
    if (tid < 128) {
        float v1a = mg_v1[0][tid], v2a = mg_v2[0][tid];
        float v1b = mg_v1[1][tid], v2b = mg_v2[1][tid];
        int   i1a = mg_i1[0][tid], i1b = mg_i1[1][tid];
        bool better = (v1b < v1a) || (v1b == v1a && i1b < i1a);
        float fv1 = better ? v1b : v1a;
        int   fi1 = better ? i1b : i1a;
        float fv2 = fminf(fminf(v2a, v2b), better ? v1a : v1b);
        int pos = (r0 + tid) * 8 + blockIdx.y;
        pv1[pos] = fv1; pidx[pos] = fi1; pv2[pos] = fv2;
    }
}

// ===== kernel: merge 8 per-block top-2 -> key or flag for exact =======
__global__ __launch_bounds__(256) void k_reduce8(const float* __restrict__ pv1,
                                                 const int* __restrict__ pidx,
                                                 const float* __restrict__ pv2,
                                                 u64* __restrict__ keys,
                                                 int* __restrict__ wlc,
                                                 int* __restrict__ wl) {
    const int j = threadIdx.x & 7;
    const int row = blockIdx.x * 32 + (threadIdx.x >> 3);
    float v1 = pv1[row * 8 + j];
    int   i1 = pidx[row * 8 + j];
    float v2 = pv2[row * 8 + j];
    #pragma unroll
    for (int m = 1; m <= 4; m <<= 1) {
        float ov1 = __shfl_xor(v1, m, 64);
        int   oi1 = __shfl_xor(i1, m, 64);
        float ov2 = __shfl_xor(v2, m, 64);
        bool better = (ov1 < v1) || (ov1 == v1 && oi1 < i1);
        float nv2 = fminf(fminf(v2, ov2), better ? v1 : ov1);
        if (better) { v1 = ov1; i1 = oi1; }
        v2 = nv2;
    }
    if (j == 0) {
        if (v2 - v1 < MARGIN_TH) {
            int p = atomicAdd(wlc, 1);
            wl[p] = row;
            keys[row] = ~0ULL;
        } else {
            keys[row] = (((u64)fsort(v1)) << 32) | (unsigned int)i1;
        }
    }
}

// ========== kernel: exact fp32 argmin for low-margin rows =============
__global__ __launch_bounds__(128) void k_exact(const float* __restrict__ x,
                                               const float* __restrict__ e,
                                               const float* __restrict__ enorm,
                                               const int* __restrict__ wlc,
                                               const int* __restrict__ wl,
                                               u64* __restrict__ keys) {
    __shared__ float xs[8][256];
    __shared__ int rowids[8];
    __shared__ u64 red[8][2];
    const int t = threadIdx.x;
    const int cnt = *wlc;
    const int c = blockIdx.x * 128 + t;
    const float en = enorm[c];

    for (int j = blockIdx.y; j * 8 < cnt; j += 16) {
        int nr = cnt - j * 8; if (nr > 8) nr = 8;
        if (t < 8) rowids[t] = (t < nr) ? wl[j * 8 + t] : 0;
        __syncthreads();
        for (int rr = 0; rr < nr; ++rr) {
            int row = rowids[rr];
            xs[rr][t] = x[(size_t)row * 256 + t];
            xs[rr][t + 128] = x[(size_t)row * 256 + t + 128];
        }
        __syncthreads();
        float dot[8];
        #pragma unroll
        for (int rr = 0; rr < 8; ++rr) dot[rr] = 0.f;
        for (int d = 0; d < 256; ++d) {
            float ev = e[d * K_CODES + c];
            #pragma unroll
            for (int rr = 0; rr < 8; ++rr) dot[rr] = fmaf(ev, xs[rr][d], dot[rr]);
        }
        #pragma unroll
        for (int rr = 0; rr < 8; ++rr) {
            float dist = fmaf(-2.f, dot[rr], en);
            u64 kk = (((u64)fsort(dist)) << 32) | (unsigned int)c;
            #pragma unroll
            for (int m = 1; m <= 32; m <<= 1) {
                u64 ok = __shfl_xor(kk, m, 64);
                kk = ok < kk ? ok : kk;
            }
            if ((t & 63) == 0) red[rr][t >> 6] = kk;
        }
        __syncthreads();
        if (t < nr) {
            u64 fk = red[t][0] < red[t][1] ? red[t][0] : red[t][1];
            atomicMin(&keys[rowids[t]], fk);
        }
        __syncthreads();
    }
}

// ========== kernel: gather quantize + per-block diff partials =========
__global__ __launch_bounds__(256) void k_gather2(const float* __restrict__ x,
                                                 const float* __restrict__ eTf,
                                                 const u64* __restrict__ keys,
                                                 float* __restrict__ out_q,
                                                 float* __restrict__ out_ind,
                                                 float* __restrict__ partial) {
    const int t = threadIdx.x, w = t >> 6, l = t & 63;
    float s = 0.f;
    #pragma unroll
    for (int p = 0; p < 2; ++p) {
        int row = blockIdx.x * 8 + p * 4 + w;
        int idx = (int)(keys[row] & 0xFFFFFFFFu);
        float4 q = *reinterpret_cast<const float4*>(&eTf[(size_t)idx * 256 + l * 4]);
        float4 xv = *reinterpret_cast<const float4*>(&x[(size_t)row * 256 + l * 4]);
        *reinterpret_cast<float4*>(&out_q[(size_t)row * 256 + l * 4]) = q;
        if (l == 0) out_ind[row] = (float)idx;
        float dx = q.x - xv.x, dy = q.y - xv.y, dz = q.z - xv.z, dw = q.w - xv.w;
        s += dx * dx + dy * dy + dz * dz + dw * dw;
    }
    #pragma unroll
    for (int m = 1; m <= 32; m <<= 1) s += __shfl_xor(s, m, 64);
    __shared__ float red[4];
    if (l == 0) red[w] = s;
    __syncthreads();
    if (t == 0) partial[blockIdx.x] = red[0] + red[1] + red[2] + red[3];
}

__global__ __launch_bounds__(256) void k_diff(const float* __restrict__ partial,
                                              float* __restrict__ out_diff) {
    const int t = threadIdx.x;
    float s = 0.f;
    for (int i = t; i < 2048; i += 256) s += partial[i];
    #pragma unroll
    for (int m = 1; m <= 32; m <<= 1) s += __shfl_xor(s, m, 64);
    __shared__ float red[4];
    if ((t & 63) == 0) red[t >> 6] = s;
    __syncthreads();
    if (t == 0) out_diff[0] = (red[0] + red[1] + red[2] + red[3]) * (1.0f / 4194304.0f);
}

// =================== FALLBACK PATH (proven R1 fp32) ===================
constexpr int FBM = 64, FBN = 256, FBK = 32, FNSPLIT = 2;

__global__ __launch_bounds__(256) void k_init_fb(u64* __restrict__ keys,
                                                 float* __restrict__ diff_slot) {
    int t = blockIdx.x * 256 + threadIdx.x;
    if (t < N_ROWS) keys[t] = ~0ULL;
    if (t == 0) diff_slot[0] = 0.0f;
}

__global__ __launch_bounds__(256) void k_argmin_fb(const float* __restrict__ x,
                                                   const float* __restrict__ e,
                                                   const float* __restrict__ enorm,
                                                   u64* __restrict__ keys) {
    __shared__ float xs[FBK][FBM + 4];
    __shared__ float es[FBK][FBN];
    const int tid = threadIdx.x;
    const int tr = tid >> 5, tc = tid & 31;
    const int row0 = blockIdx.x * FBM;
    const int cbase = blockIdx.y * (K_CODES / FNSPLIT);
    float minv[8]; int mini[8];
    #pragma unroll
    for (int i = 0; i < 8; ++i) { minv[i] = 1e30f; mini[i] = 0; }
    for (int chunk = 0; chunk < (K_CODES / FNSPLIT) / FBN; ++chunk) {
        const int c0 = cbase + chunk * FBN;
        float acc[8][8];
        #pragma unroll
        for (int i = 0; i < 8; ++i)
            #pragma unroll
            for (int j = 0; j < 8; ++j) acc[i][j] = 0.f;
        for (int kt = 0; kt < D_DIM / FBK; ++kt) {
            #pragma unroll
            for (int l2 = 0; l2 < 2; ++l2) {
                int q = tid + 256 * l2, r = q >> 3, kq = q & 7;
                float4 v = *reinterpret_cast<const float4*>(&x[(row0 + r) * D_DIM + kt * FBK + kq * 4]);
                xs[kq * 4 + 0][r] = v.x; xs[kq * 4 + 1][r] = v.y;
                xs[kq * 4 + 2][r] = v.z; xs[kq * 4 + 3][r] = v.w;
            }
            #pragma unroll
            for (int l2 = 0; l2 < 8; ++l2) {
                int q = tid + 256 * l2, k = q >> 6, cq = q & 63;
                float4 v = *reinterpret_cast<const float4*>(&e[(kt * FBK + k) * K_CODES + c0 + cq * 4]);
                *reinterpret_cast<float4*>(&es[k][cq * 4]) = v;
            }
            __syncthreads();
            #pragma unroll 8
            for (int k = 0; k < FBK; ++k) {
                float4 a0 = *reinterpret_cast<const float4*>(&xs[k][tr * 8]);
                float4 a1 = *reinterpret_cast<const float4*>(&xs[k][tr * 8 + 4]);
                float4 b0 = *reinterpret_cast<const float4*>(&es[k][tc * 8]);
                float4 b1 = *reinterpret_cast<const float4*>(&es[k][tc * 8 + 4]);
                float a[8] = {a0.x, a0.y, a0.z, a0.w, a1.x, a1.y, a1.z, a1.w};
                float b[8] = {b0.x, b0.y, b0.z, b0.w, b1.x, b1.y, b1.z, b1.w};
                #pragma unroll
                for (int i = 0; i < 8; ++i)
                    #pragma unroll
                    for (int j = 0; j < 8; ++j) acc[i][j] = fmaf(a[i], b[j], acc[i][j]);
            }
            __syncthreads();
        }
        #pragma unroll
        for (int j = 0; j < 8; ++j) {
            int c = c0 + tc * 8 + j;
            float en = enorm[c];
            #pragma unroll
            for (int i = 0; i < 8; ++i) {
                float dv = fmaf(-2.0f, acc[i][j], en);
                if (dv < minv[i]) { minv[i] = dv; mini[i] = c; }
            }
        }
    }
    #pragma unroll
    for (int m = 16; m >= 1; m >>= 1) {
        #pragma unroll
        for (int i = 0; i < 8; ++i) {
            float ov = __shfl_xor(minv[i], m, 64);
            int oi = __shfl_xor(mini[i], m, 64);
            if (ov < minv[i] || (ov == minv[i] && oi < mini[i])) { minv[i] = ov; mini[i] = oi; }
        }
    }
    if (tc == 0) {
        #pragma unroll
        for (int i = 0; i < 8; ++i) {
            int row = row0 + tr * 8 + i;
            u64 key = (((u64)fsort(minv[i])) << 32) | (unsigned int)mini[i];
            atomicMin(&keys[row], key);
        }
    }
}

__global__ __launch_bounds__(256) void k_gather_fb(const float* __restrict__ x,
                                                   const float* __restrict__ e,
                                                   const u64* __restrict__ keys,
                                                   float* __restrict__ out_q,
                                                   float* __restrict__ out_diff,
                                                   float* __restrict__ out_ind) {
    int row = blockIdx.x, d = threadIdx.x;
    int idx = (int)(keys[row] & 0xFFFFFFFFu);
    float q = e[d * K_CODES + idx];
    float xv = x[row * D_DIM + d];
    out_q[row * D_DIM + d] = q;
    if (d == 0) out_ind[row] = (float)idx;
    float sq = q - xv; sq *= sq;
    #pragma unroll
    for (int m = 32; m >= 1; m >>= 1) sq += __shfl_xor(sq, m, 64);
    __shared__ float red[4];
    if ((d & 63) == 0) red[d >> 6] = sq;
    __syncthreads();
    if (d == 0) {
        float s = (red[0] + red[1] + red[2] + red[3]) * (1.0f / (float)(N_ROWS * D_DIM));
        atomicAdd(out_diff, s);
    }
}

// ======================= launcher =====================================
extern "C" void kernel_launch(void* const* d_in, const int* in_sizes, int n_in,
                              void* d_out, int out_size, void* d_ws, size_t ws_size,
                              hipStream_t stream) {
    const float* x = (const float*)d_in[0];
    const float* e = (const float*)d_in[1];
    float* out = (float*)d_out;
    float* out_q = out;
    float* out_diff = out + OFF_DIFF;
    float* out_ind = out + OFF_IND;
    char* ws = (char*)d_ws;

    if (ws_size >= WS_NEED) {
        ushort_t* xh  = (ushort_t*)(ws + XH_OFF);
        ushort_t* xl  = (ushort_t*)(ws + XL_OFF);
        ushort_t* ehT = (ushort_t*)(ws + EHT_OFF);
        ushort_t* elT = (ushort_t*)(ws + ELT_OFF);
        float* eTf    = (float*)(ws + ETF_OFF);
        float* enorm  = (float*)(ws + ENORM_OFF);
        u64* keys     = (u64*)(ws + KEYS_OFF);
        float* pv1    = (float*)(ws + PV1_OFF);
        int* pidx     = (int*)(ws + PIDX_OFF);
        float* pv2    = (float*)(ws + PV2_OFF);
        int* wlc      = (int*)(ws + WLC_OFF);
        int* wl       = (int*)(ws + WL_OFF);
        float* part   = (float*)(ws + PART_OFF);

        k_split_x <<<2048, 256, 0, stream>>>(x, xh, xl);
        k_split_eT<<<128, 256, 0, stream>>>(e, ehT, elT, eTf);
        k_norms   <<<32, 256, 0, stream>>>(e, enorm, wlc);
        k_mfma    <<<dim3(128, 8), 256, 0, stream>>>(xh, xl, ehT, elT, enorm, pv1, pidx, pv2);
        k_reduce8 <<<512, 256, 0, stream>>>(pv1, pidx, pv2, keys, wlc, wl);
        k_exact   <<<dim3(64, 16), 128, 0, stream>>>(x, e, enorm, wlc, wl, keys);
        k_gather2 <<<2048, 256, 0, stream>>>(x, eTf, keys, out_q, out_ind, part);
        k_diff    <<<1, 256, 0, stream>>>(part, out_diff);
    } else {
        float* enorm = (float*)ws;
        u64* keys = (u64*)(ws + 32768);
        k_init_fb  <<<64, 256, 0, stream>>>(keys, out_diff);
        k_norms    <<<32, 256, 0, stream>>>(e, enorm, (int*)(ws + 163840));
        k_argmin_fb<<<dim3(N_ROWS / FBM, FNSPLIT), 256, 0, stream>>>(x, e, enorm, keys);
        k_gather_fb<<<N_ROWS, 256, 0, stream>>>(x, e, keys, out_q, out_diff, out_ind);
    }
}

// Round 8
// 338.732 us; speedup vs baseline: 1.3121x; 1.3121x over previous
//
#include <hip/hip_runtime.h>

typedef unsigned long long u64;
typedef unsigned short ushort_t;
typedef float f32x4 __attribute__((ext_vector_type(4)));
typedef short bf16x8 __attribute__((ext_vector_type(8)));
typedef unsigned short ushort8 __attribute__((ext_vector_type(8)));

#define D_DIM   256
#define N_ROWS  16384
#define K_CODES 8192
#define OFF_DIFF 4194304
#define OFF_IND  4194305

// ---------------- ws layout (bytes) for the MFMA path ----------------
#define XH_OFF    0ULL
#define XL_OFF    8388608ULL
#define EHT_OFF   16777216ULL
#define ELT_OFF   20971520ULL
#define ETF_OFF   25165824ULL
#define ENORM_OFF 33554432ULL
#define KEYS_OFF  33587200ULL
#define PV1_OFF   33718272ULL
#define PIDX_OFF  37912576ULL
#define PV2_OFF   42106880ULL
#define WLC_OFF   46301184ULL
#define WL_OFF    46301440ULL
#define PART_OFF  46366976ULL
#define WS_NEED   46375168ULL

#define MARGIN_TH 0.08f

#define GLD(gp, lp) __builtin_amdgcn_global_load_lds( \
    (const __attribute__((address_space(1))) unsigned int*)(const void*)(gp), \
    (__attribute__((address_space(3))) unsigned int*)(void*)(lp), 16, 0, 0)

__device__ __forceinline__ unsigned int fsort(float f) {
    unsigned int u = __float_as_uint(f);
    return (u & 0x80000000u) ? ~u : (u | 0x80000000u);
}
__device__ __forceinline__ ushort_t f2bf(float f) {
    unsigned int u = __float_as_uint(f);
    unsigned int r = (u + 0x7fffu + ((u >> 16) & 1u)) >> 16;
    return (ushort_t)r;
}
__device__ __forceinline__ float bf2f(ushort_t h) {
    return __uint_as_float(((unsigned int)h) << 16);
}

// ================= kernel: split x into bf16 hi/lo =================
__global__ __launch_bounds__(256) void k_split_x(const float* __restrict__ x,
                                                 ushort_t* __restrict__ xh,
                                                 ushort_t* __restrict__ xl) {
    int base = (blockIdx.x * 256 + threadIdx.x) * 8;
    float4 v0 = *reinterpret_cast<const float4*>(&x[base]);
    float4 v1 = *reinterpret_cast<const float4*>(&x[base + 4]);
    float f[8] = {v0.x, v0.y, v0.z, v0.w, v1.x, v1.y, v1.z, v1.w};
    ushort8 h, l;
    #pragma unroll
    for (int i = 0; i < 8; ++i) {
        ushort_t hb = f2bf(f[i]);
        h[i] = (short)hb;
        l[i] = (short)f2bf(f[i] - bf2f(hb));
    }
    *reinterpret_cast<ushort8*>(&xh[base]) = h;
    *reinterpret_cast<ushort8*>(&xl[base]) = l;
}

// ===== kernel: transpose e -> eT (f32) + bf16 hi/lo splits of eT ======
__global__ __launch_bounds__(256) void k_split_eT(const float* __restrict__ e,
                                                  ushort_t* __restrict__ ehT,
                                                  ushort_t* __restrict__ elT,
                                                  float* __restrict__ eTf) {
    __shared__ float tile[64][257];
    const int t = threadIdx.x;
    const int c0 = blockIdx.x * 64;
    for (int it = 0; it < 64; ++it) {
        int d = it * 4 + (t >> 6);
        tile[t & 63][d] = e[d * K_CODES + c0 + (t & 63)];
    }
    __syncthreads();
    for (int cc = 0; cc < 64; ++cc) {
        float v = tile[cc][t];
        ushort_t hb = f2bf(v);
        size_t o = (size_t)(c0 + cc) * 256 + t;
        ehT[o] = hb;
        elT[o] = f2bf(v - bf2f(hb));
        eTf[o] = v;
    }
}

// ================= kernel: ||e_k||^2 (+ worklist count init) ==========
__global__ __launch_bounds__(256) void k_norms(const float* __restrict__ e,
                                               float* __restrict__ enorm,
                                               int* __restrict__ wlc) {
    int k = blockIdx.x * 256 + threadIdx.x;
    float s = 0.f;
    #pragma unroll 8
    for (int d = 0; d < D_DIM; ++d) {
        float v = e[d * K_CODES + k];
        s = fmaf(v, v, s);
    }
    enorm[k] = s;
    if (k == 0) *wlc = 0;
}

// ============ kernel: MFMA distance GEMM + in-lane top-2 ==============
// R5 = R3 grid (128 rows x 128 codes per block, grid (128,64) -- x-tile
// staged ONCE per block, dispatch-adjacent blocks share the e-tile in L2)
// + R4's transposed operands (A = codes, B = x-rows) so the top-2 fold is
// in-lane, + R4's conflict-free ^((row>>1)&3) swizzle. The heavy reduce
// runs once per block on a cheap 2-shuffle-step path.
__global__ __launch_bounds__(256, 3) void k_mfma(const ushort_t* __restrict__ xh,
                                                 const ushort_t* __restrict__ xl,
                                                 const ushort_t* __restrict__ ehT,
                                                 const ushort_t* __restrict__ elT,
                                                 const float* __restrict__ enorm,
                                                 float* __restrict__ pv1,
                                                 int* __restrict__ pidx,
                                                 float* __restrict__ pv2) {
    __shared__ short Ah[4096], Al[4096], Bh[4096], Bl[4096];
    __shared__ float mg_v1[2][128];
    __shared__ float mg_v2[2][128];
    __shared__ int   mg_i1[2][128];
    const int tid = threadIdx.x;
    const int l = tid & 63, w = tid >> 6;
    const int wm = w >> 1, wn = w & 1;   // wm: x-row half, wn: code half
    const int r0 = blockIdx.x * 128;
    const int c0 = blockIdx.y * 128;

    // staging: lane l -> local row rl = l>>2, slot = l&3; LDS[row][slot]
    // holds k-chunk g = slot ^ ((row>>1)&3)  (2-way-free swizzle, m136).
    const int rl = l >> 2;
    const int g = (l & 3) ^ ((rl >> 1) & 3);
    const int rowL0 = w * 32 + rl;
    const size_t aoff = (size_t)(c0 + rowL0) * 256 + g * 8;  // e side (A)
    const size_t boff = (size_t)(r0 + rowL0) * 256 + g * 8;  // x side (B)
    short* Adst  = Ah + w * 1024;   // inst1 at +512 (rows +16)
    short* Aldst = Al + w * 1024;
    short* Bdst  = Bh + w * 1024;
    short* Bldst = Bl + w * 1024;

    const int fr = l & 15, kg = l >> 4;

    f32x4 acc[4][4];
    #pragma unroll
    for (int mi = 0; mi < 4; ++mi)
        #pragma unroll
        for (int ni = 0; ni < 4; ++ni)
            #pragma unroll
            for (int q = 0; q < 4; ++q) acc[mi][ni][q] = 0.f;

    for (int kt = 0; kt < 8; ++kt) {
        const int ko = kt * 32;
        GLD(&ehT[aoff + ko], Adst);
        GLD(&ehT[aoff + ko + 4096], Adst + 512);
        GLD(&elT[aoff + ko], Aldst);
        GLD(&elT[aoff + ko + 4096], Aldst + 512);
        GLD(&xh[boff + ko], Bdst);
        GLD(&xh[boff + ko + 4096], Bdst + 512);
        GLD(&xl[boff + ko], Bldst);
        GLD(&xl[boff + ko + 4096], Bldst + 512);
        __syncthreads();

        bf16x8 a_h[4], a_l[4], b_h[4], b_l[4];
        #pragma unroll
        for (int mi = 0; mi < 4; ++mi) {      // A rows = codes
            int rf = wn * 64 + mi * 16 + fr;
            int idx = rf * 32 + ((kg ^ ((rf >> 1) & 3)) * 8);
            a_h[mi] = *reinterpret_cast<const bf16x8*>(&Ah[idx]);
            a_l[mi] = *reinterpret_cast<const bf16x8*>(&Al[idx]);
        }
        #pragma unroll
        for (int ni = 0; ni < 4; ++ni) {      // B cols = x-rows
            int cf = wm * 64 + ni * 16 + fr;
            int idx = cf * 32 + ((kg ^ ((cf >> 1) & 3)) * 8);
            b_h[ni] = *reinterpret_cast<const bf16x8*>(&Bh[idx]);
            b_l[ni] = *reinterpret_cast<const bf16x8*>(&Bl[idx]);
        }
        #pragma unroll
        for (int mi = 0; mi < 4; ++mi)
            #pragma unroll
            for (int ni = 0; ni < 4; ++ni) {
                acc[mi][ni] = __builtin_amdgcn_mfma_f32_16x16x32_bf16(a_h[mi], b_h[ni], acc[mi][ni], 0, 0, 0);
                acc[mi][ni] = __builtin_amdgcn_mfma_f32_16x16x32_bf16(a_h[mi], b_l[ni], acc[mi][ni], 0, 0, 0);
                acc[mi][ni] = __builtin_amdgcn_mfma_f32_16x16x32_bf16(a_l[mi], b_h[ni], acc[mi][ni], 0, 0, 0);
            }
        __syncthreads();
    }

    // epilogue: dist = ||e||^2 - 2 x.e ; in-lane fold of 16 code
    // candidates per ni, then 2-step kg reduce + wn-half LDS merge.
    float v1[4], v2[4];
    int   i1[4];
    #pragma unroll
    for (int ni = 0; ni < 4; ++ni) { v1[ni] = 1e30f; v2[ni] = 1e30f; i1[ni] = 0; }

    float en_r[4][4];
    #pragma unroll
    for (int mi = 0; mi < 4; ++mi)
        #pragma unroll
        for (int r = 0; r < 4; ++r)
            en_r[mi][r] = enorm[c0 + wn * 64 + mi * 16 + kg * 4 + r];
    const int cwn = c0 + wn * 64 + kg * 4;

    #pragma unroll
    for (int ni = 0; ni < 4; ++ni)
        #pragma unroll
        for (int mi = 0; mi < 4; ++mi)
            #pragma unroll
            for (int r = 0; r < 4; ++r) {
                float dv = fmaf(-2.f, acc[mi][ni][r], en_r[mi][r]);
                int c = cwn + mi * 16 + r;
                if (dv < v1[ni]) { v2[ni] = v1[ni]; v1[ni] = dv; i1[ni] = c; }
                else v2[ni] = fminf(v2[ni], dv);
            }

    #pragma unroll
    for (int ni = 0; ni < 4; ++ni) {
        #pragma unroll
        for (int m = 16; m <= 32; m <<= 1) {
            float ov1 = __shfl_xor(v1[ni], m, 64);
            int   oi1 = __shfl_xor(i1[ni], m, 64);
            float ov2 = __shfl_xor(v2[ni], m, 64);
            bool better = (ov1 < v1[ni]) || (ov1 == v1[ni] && oi1 < i1[ni]);
            float nv2 = fminf(fminf(v2[ni], ov2), better ? v1[ni] : ov1);
            if (better) { v1[ni] = ov1; i1[ni] = oi1; }
            v2[ni] = nv2;
        }
        if (l < 16) {
            int lr = wm * 64 + ni * 16 + l;   // local x-row 0..127
            mg_v1[wn][lr] = v1[ni];
            mg_i1[wn][lr] = i1[ni];
            mg_v2[wn][lr] = v2[ni];
        }
    }

    __syncthreads();
    if (tid < 128) {
        float v1a = mg_v1[0][tid], v2a = mg_v2[0][tid];
        float v1b = mg_v1[1][tid], v2b = mg_v2[1][tid];
        int   i1a = mg_i1[0][tid], i1b = mg_i1[1][tid];
        bool better = (v1b < v1a) || (v1b == v1a && i1b < i1a);
        float fv1 = better ? v1b : v1a;
        int   fi1 = better ? i1b : i1a;
        float fv2 = fminf(fminf(v2a, v2b), better ? v1a : v1b);
        int pos = (r0 + tid) * 64 + blockIdx.y;
        pv1[pos] = fv1; pidx[pos] = fi1; pv2[pos] = fv2;
    }
}

// ===== kernel: merge 64 per-block top-2 -> key or flag for exact ======
__global__ __launch_bounds__(256) void k_reduce(const float* __restrict__ pv1,
                                                const int* __restrict__ pidx,
                                                const float* __restrict__ pv2,
                                                u64* __restrict__ keys,
                                                int* __restrict__ wlc,
                                                int* __restrict__ wl) {
    const int w = threadIdx.x >> 6, l = threadIdx.x & 63;
    const int row = blockIdx.x * 4 + w;
    float v1 = pv1[row * 64 + l];
    int   i1 = pidx[row * 64 + l];
    float v2 = pv2[row * 64 + l];
    #pragma unroll
    for (int m = 1; m <= 32; m <<= 1) {
        float ov1 = __shfl_xor(v1, m, 64);
        int   oi1 = __shfl_xor(i1, m, 64);
        float ov2 = __shfl_xor(v2, m, 64);
        bool better = (ov1 < v1) || (ov1 == v1 && oi1 < i1);
        float nv2 = fminf(fminf(v2, ov2), better ? v1 : ov1);
        if (better) { v1 = ov1; i1 = oi1; }
        v2 = nv2;
    }
    if (l == 0) {
        if (v2 - v1 < MARGIN_TH) {
            int p = atomicAdd(wlc, 1);
            wl[p] = row;
            keys[row] = ~0ULL;
        } else {
            keys[row] = (((u64)fsort(v1)) << 32) | (unsigned int)i1;
        }
    }
}

// ========== kernel: exact fp32 argmin for low-margin rows =============
__global__ __launch_bounds__(128) void k_exact(const float* __restrict__ x,
                                               const float* __restrict__ e,
                                               const float* __restrict__ enorm,
                                               const int* __restrict__ wlc,
                                               const int* __restrict__ wl,
                                               u64* __restrict__ keys) {
    __shared__ float xs[8][256];
    __shared__ int rowids[8];
    __shared__ u64 red[8][2];
    const int t = threadIdx.x;
    const int cnt = *wlc;
    const int c = blockIdx.x * 128 + t;
    const float en = enorm[c];

    for (int j = blockIdx.y; j * 8 < cnt; j += 16) {
        int nr = cnt - j * 8; if (nr > 8) nr = 8;
        if (t < 8) rowids[t] = (t < nr) ? wl[j * 8 + t] : 0;
        __syncthreads();
        for (int rr = 0; rr < nr; ++rr) {
            int row = rowids[rr];
            xs[rr][t] = x[(size_t)row * 256 + t];
            xs[rr][t + 128] = x[(size_t)row * 256 + t + 128];
        }
        __syncthreads();
        float dot[8];
        #pragma unroll
        for (int rr = 0; rr < 8; ++rr) dot[rr] = 0.f;
        for (int d = 0; d < 256; ++d) {
            float ev = e[d * K_CODES + c];
            #pragma unroll
            for (int rr = 0; rr < 8; ++rr) dot[rr] = fmaf(ev, xs[rr][d], dot[rr]);
        }
        #pragma unroll
        for (int rr = 0; rr < 8; ++rr) {
            float dist = fmaf(-2.f, dot[rr], en);
            u64 kk = (((u64)fsort(dist)) << 32) | (unsigned int)c;
            #pragma unroll
            for (int m = 1; m <= 32; m <<= 1) {
                u64 ok = __shfl_xor(kk, m, 64);
                kk = ok < kk ? ok : kk;
            }
            if ((t & 63) == 0) red[rr][t >> 6] = kk;
        }
        __syncthreads();
        if (t < nr) {
            u64 fk = red[t][0] < red[t][1] ? red[t][0] : red[t][1];
            atomicMin(&keys[rowids[t]], fk);
        }
        __syncthreads();
    }
}

// ========== kernel: gather quantize + per-block diff partials =========
__global__ __launch_bounds__(256) void k_gather2(const float* __restrict__ x,
                                                 const float* __restrict__ eTf,
                                                 const u64* __restrict__ keys,
                                                 float* __restrict__ out_q,
                                                 float* __restrict__ out_ind,
                                                 float* __restrict__ partial) {
    const int t = threadIdx.x, w = t >> 6, l = t & 63;
    float s = 0.f;
    #pragma unroll
    for (int p = 0; p < 2; ++p) {
        int row = blockIdx.x * 8 + p * 4 + w;
        int idx = (int)(keys[row] & 0xFFFFFFFFu);
        float4 q = *reinterpret_cast<const float4*>(&eTf[(size_t)idx * 256 + l * 4]);
        float4 xv = *reinterpret_cast<const float4*>(&x[(size_t)row * 256 + l * 4]);
        *reinterpret_cast<float4*>(&out_q[(size_t)row * 256 + l * 4]) = q;
        if (l == 0) out_ind[row] = (float)idx;
        float dx = q.x - xv.x, dy = q.y - xv.y, dz = q.z - xv.z, dw = q.w - xv.w;
        s += dx * dx + dy * dy + dz * dz + dw * dw;
    }
    #pragma unroll
    for (int m = 1; m <= 32; m <<= 1) s += __shfl_xor(s, m, 64);
    __shared__ float red[4];
    if (l == 0) red[w] = s;
    __syncthreads();
    if (t == 0) partial[blockIdx.x] = red[0] + red[1] + red[2] + red[3];
}

__global__ __launch_bounds__(256) void k_diff(const float* __restrict__ partial,
                                              float* __restrict__ out_diff) {
    const int t = threadIdx.x;
    float s = 0.f;
    for (int i = t; i < 2048; i += 256) s += partial[i];
    #pragma unroll
    for (int m = 1; m <= 32; m <<= 1) s += __shfl_xor(s, m, 64);
    __shared__ float red[4];
    if ((t & 63) == 0) red[t >> 6] = s;
    __syncthreads();
    if (t == 0) out_diff[0] = (red[0] + red[1] + red[2] + red[3]) * (1.0f / 4194304.0f);
}

// =================== FALLBACK PATH (proven R1 fp32) ===================
constexpr int FBM = 64, FBN = 256, FBK = 32, FNSPLIT = 2;

__global__ __launch_bounds__(256) void k_init_fb(u64* __restrict__ keys,
                                                 float* __restrict__ diff_slot) {
    int t = blockIdx.x * 256 + threadIdx.x;
    if (t < N_ROWS) keys[t] = ~0ULL;
    if (t == 0) diff_slot[0] = 0.0f;
}

__global__ __launch_bounds__(256) void k_argmin_fb(const float* __restrict__ x,
                                                   const float* __restrict__ e,
                                                   const float* __restrict__ enorm,
                                                   u64* __restrict__ keys) {
    __shared__ float xs[FBK][FBM + 4];
    __shared__ float es[FBK][FBN];
    const int tid = threadIdx.x;
    const int tr = tid >> 5, tc = tid & 31;
    const int row0 = blockIdx.x * FBM;
    const int cbase = blockIdx.y * (K_CODES / FNSPLIT);
    float minv[8]; int mini[8];
    #pragma unroll
    for (int i = 0; i < 8; ++i) { minv[i] = 1e30f; mini[i] = 0; }
    for (int chunk = 0; chunk < (K_CODES / FNSPLIT) / FBN; ++chunk) {
        const int c0 = cbase + chunk * FBN;
        float acc[8][8];
        #pragma unroll
        for (int i = 0; i < 8; ++i)
            #pragma unroll
            for (int j = 0; j < 8; ++j) acc[i][j] = 0.f;
        for (int kt = 0; kt < D_DIM / FBK; ++kt) {
            #pragma unroll
            for (int l2 = 0; l2 < 2; ++l2) {
                int q = tid + 256 * l2, r = q >> 3, kq = q & 7;
                float4 v = *reinterpret_cast<const float4*>(&x[(row0 + r) * D_DIM + kt * FBK + kq * 4]);
                xs[kq * 4 + 0][r] = v.x; xs[kq * 4 + 1][r] = v.y;
                xs[kq * 4 + 2][r] = v.z; xs[kq * 4 + 3][r] = v.w;
            }
            #pragma unroll
            for (int l2 = 0; l2 < 8; ++l2) {
                int q = tid + 256 * l2, k = q >> 6, cq = q & 63;
                float4 v = *reinterpret_cast<const float4*>(&e[(kt * FBK + k) * K_CODES + c0 + cq * 4]);
                *reinterpret_cast<float4*>(&es[k][cq * 4]) = v;
            }
            __syncthreads();
            #pragma unroll 8
            for (int k = 0; k < FBK; ++k) {
                float4 a0 = *reinterpret_cast<const float4*>(&xs[k][tr * 8]);
                float4 a1 = *reinterpret_cast<const float4*>(&xs[k][tr * 8 + 4]);
                float4 b0 = *reinterpret_cast<const float4*>(&es[k][tc * 8]);
                float4 b1 = *reinterpret_cast<const float4*>(&es[k][tc * 8 + 4]);
                float a[8] = {a0.x, a0.y, a0.z, a0.w, a1.x, a1.y, a1.z, a1.w};
                float b[8] = {b0.x, b0.y, b0.z, b0.w, b1.x, b1.y, b1.z, b1.w};
                #pragma unroll
                for (int i = 0; i < 8; ++i)
                    #pragma unroll
                    for (int j = 0; j < 8; ++j) acc[i][j] = fmaf(a[i], b[j], acc[i][j]);
            }
            __syncthreads();
        }
        #pragma unroll
        for (int j = 0; j < 8; ++j) {
            int c = c0 + tc * 8 + j;
            float en = enorm[c];
            #pragma unroll
            for (int i = 0; i < 8; ++i) {
                float dv = fmaf(-2.0f, acc[i][j], en);
                if (dv < minv[i]) { minv[i] = dv; mini[i] = c; }
            }
        }
    }
    #pragma unroll
    for (int m = 16; m >= 1; m >>= 1) {
        #pragma unroll
        for (int i = 0; i < 8; ++i) {
            float ov = __shfl_xor(minv[i], m, 64);
            int oi = __shfl_xor(mini[i], m, 64);
            if (ov < minv[i] || (ov == minv[i] && oi < mini[i])) { minv[i] = ov; mini[i] = oi; }
        }
    }
    if (tc == 0) {
        #pragma unroll
        for (int i = 0; i < 8; ++i) {
            int row = row0 + tr * 8 + i;
            u64 key = (((u64)fsort(minv[i])) << 32) | (unsigned int)mini[i];
            atomicMin(&keys[row], key);
        }
    }
}

__global__ __launch_bounds__(256) void k_gather_fb(const float* __restrict__ x,
                                                   const float* __restrict__ e,
                                                   const u64* __restrict__ keys,
                                                   float* __restrict__ out_q,
                                                   float* __restrict__ out_diff,
                                                   float* __restrict__ out_ind) {
    int row = blockIdx.x, d = threadIdx.x;
    int idx = (int)(keys[row] & 0xFFFFFFFFu);
    float q = e[d * K_CODES + idx];
    float xv = x[row * D_DIM + d];
    out_q[row * D_DIM + d] = q;
    if (d == 0) out_ind[row] = (float)idx;
    float sq = q - xv; sq *= sq;
    #pragma unroll
    for (int m = 32; m >= 1; m >>= 1) sq += __shfl_xor(sq, m, 64);
    __shared__ float red[4];
    if ((d & 63) == 0) red[d >> 6] = sq;
    __syncthreads();
    if (d == 0) {
        float s = (red[0] + red[1] + red[2] + red[3]) * (1.0f / (float)(N_ROWS * D_DIM));
        atomicAdd(out_diff, s);
    }
}

// ======================= launcher =====================================
extern "C" void kernel_launch(void* const* d_in, const int* in_sizes, int n_in,
                              void* d_out, int out_size, void* d_ws, size_t ws_size,
                              hipStream_t stream) {
    const float* x = (const float*)d_in[0];
    const float* e = (const float*)d_in[1];
    float* out = (float*)d_out;
    float* out_q = out;
    float* out_diff = out + OFF_DIFF;
    float* out_ind = out + OFF_IND;
    char* ws = (char*)d_ws;

    if (ws_size >= WS_NEED) {
        ushort_t* xh  = (ushort_t*)(ws + XH_OFF);
        ushort_t* xl  = (ushort_t*)(ws + XL_OFF);
        ushort_t* ehT = (ushort_t*)(ws + EHT_OFF);
        ushort_t* elT = (ushort_t*)(ws + ELT_OFF);
        float* eTf    = (float*)(ws + ETF_OFF);
        float* enorm  = (float*)(ws + ENORM_OFF);
        u64* keys     = (u64*)(ws + KEYS_OFF);
        float* pv1    = (float*)(ws + PV1_OFF);
        int* pidx     = (int*)(ws + PIDX_OFF);
        float* pv2    = (float*)(ws + PV2_OFF);
        int* wlc      = (int*)(ws + WLC_OFF);
        int* wl       = (int*)(ws + WL_OFF);
        float* part   = (float*)(ws + PART_OFF);

        k_split_x <<<2048, 256, 0, stream>>>(x, xh, xl);
        k_split_eT<<<128, 256, 0, stream>>>(e, ehT, elT, eTf);
        k_norms   <<<32, 256, 0, stream>>>(e, enorm, wlc);
        k_mfma    <<<dim3(128, 64), 256, 0, stream>>>(xh, xl, ehT, elT, enorm, pv1, pidx, pv2);
        k_reduce  <<<4096, 256, 0, stream>>>(pv1, pidx, pv2, keys, wlc, wl);
        k_exact   <<<dim3(64, 16), 128, 0, stream>>>(x, e, enorm, wlc, wl, keys);
        k_gather2 <<<2048, 256, 0, stream>>>(x, eTf, keys, out_q, out_ind, part);
        k_diff    <<<1, 256, 0, stream>>>(part, out_diff);
    } else {
        float* enorm = (float*)ws;
        u64* keys = (u64*)(ws + 32768);
        k_init_fb  <<<64, 256, 0, stream>>>(keys, out_diff);
        k_norms    <<<32, 256, 0, stream>>>(e, enorm, (int*)(ws + 163840));
        k_argmin_fb<<<dim3(N_ROWS / FBM, FNSPLIT), 256, 0, stream>>>(x, e, enorm, keys);
        k_gather_fb<<<N_ROWS, 256, 0, stream>>>(x, e, keys, out_q, out_diff, out_ind);
    }
}